// Round 3
// baseline (2452.292 us; speedup 1.0000x reference)
//
#include <hip/hip_runtime.h>
#include <cstdint>
#include <cstddef>

#define T_SEQ 2048
#define BATCH 64
#define DIN   256
#define HDIM  256

typedef float    f32x4 __attribute__((ext_vector_type(4)));
typedef short    s16x8 __attribute__((ext_vector_type(8)));
typedef uint32_t u32x2 __attribute__((ext_vector_type(2)));

// f32 pair -> packed bf16 (RNE), no builtin on gfx950 (learn_hip m240) -> asm
__device__ inline uint32_t cvt_pk_bf16(float lo, float hi) {
  uint32_t r;
  asm("v_cvt_pk_bf16_f32 %0, %1, %2" : "=v"(r) : "v"(lo), "v"(hi));
  return r;
}

// tanh(x) = 1 - 2/(1+e^{2x}); e^{2x} = exp2(2*log2(e)*x).
// Saturates correctly: x>>0: exp2->inf, rcp->0 -> 1. x<<0: exp2->0 -> -1.
// v_exp_f32 / v_rcp_f32 via asm (no portable builtin guaranteed).
__device__ inline float fast_tanh(float x) {
  float s = x * 2.885390081777927f;   // 2/ln(2)
  float e2, r;
  asm("v_exp_f32 %0, %1" : "=v"(e2) : "v"(s));
  float d = 1.0f + e2;
  asm("v_rcp_f32 %0, %1" : "=v"(r) : "v"(d));
  return __builtin_fmaf(-2.0f, r, 1.0f);
}

// ---------------------------------------------------------------------------
// Phase 1: out[m][j] = sum_i x[m][i]*w_ih[j][i] + b_ih[j] + b_hh[j]
// m = t*B+b (131072 rows). One WG = 64 m-rows. C^T orientation:
//   A = w_ih rows (j), held as bf16 frags in registers (128 VGPR/wave)
//   B = x rows, staged to LDS as bf16 (padded stride 528B -> 2-way = free)
//   D[j][m]: lane holds cols m=(lane&15), rows j0..j0+3 -> float4 store.
// ---------------------------------------------------------------------------
__global__ __launch_bounds__(256, 2) void rnn_xproj(
    const float* __restrict__ x, const float* __restrict__ w_ih,
    const float* __restrict__ b_ih, const float* __restrict__ b_hh,
    float* __restrict__ out)
{
  __shared__ __align__(16) unsigned short xtile[64 * 264]; // 64 rows, 528B stride
  const int tid  = threadIdx.x;
  const int wv   = tid >> 6;
  const int lane = tid & 63;
  const int q    = lane >> 4;
  const int r16  = lane & 15;
  const int m0   = blockIdx.x * 64;

  // A-fragments: lane l holds A[j = l&15][k = 32*kk + 8*(l>>4) + i], i=0..7.
  // A and B use the SAME k-placement, so any consistent permutation is exact.
  s16x8 afr[4][8];
#pragma unroll
  for (int nn = 0; nn < 4; ++nn) {
    const int j = 64 * wv + 16 * nn + r16;
#pragma unroll
    for (int kk = 0; kk < 8; ++kk) {
      const int k0 = kk * 32 + q * 8;
      f32x4 lo = *(const f32x4*)(w_ih + j * DIN + k0);
      f32x4 hi = *(const f32x4*)(w_ih + j * DIN + k0 + 4);
      union { s16x8 v; uint32_t u[4]; } fu;
      fu.u[0] = cvt_pk_bf16(lo.x, lo.y);
      fu.u[1] = cvt_pk_bf16(lo.z, lo.w);
      fu.u[2] = cvt_pk_bf16(hi.x, hi.y);
      fu.u[3] = cvt_pk_bf16(hi.z, hi.w);
      afr[nn][kk] = fu.v;
    }
  }

  f32x4 bs[4];
#pragma unroll
  for (int nn = 0; nn < 4; ++nn) {
    const int j0 = 64 * wv + 16 * nn + 4 * q;
    f32x4 a = *(const f32x4*)(b_ih + j0);
    f32x4 b = *(const f32x4*)(b_hh + j0);
    bs[nn] = a + b;
  }

  // stage x block -> LDS bf16: 256 thr x 4 floats x 16 iters = 64x256
#pragma unroll
  for (int s = 0; s < 16; ++s) {
    const int o   = s * 1024 + tid * 4;   // float index within the 64x256 tile
    const int row = o >> 8;
    const int col = o & 255;
    f32x4 v = *(const f32x4*)(x + (size_t)m0 * DIN + o);
    u32x2 pk;
    pk.x = cvt_pk_bf16(v.x, v.y);
    pk.y = cvt_pk_bf16(v.z, v.w);
    *(u32x2*)((char*)xtile + row * 528 + col * 2) = pk;
  }
  __syncthreads();

#pragma unroll
  for (int mm = 0; mm < 4; ++mm) {
    s16x8 bfr[8];
#pragma unroll
    for (int kk = 0; kk < 8; ++kk)
      bfr[kk] = *(const s16x8*)((const char*)xtile +
                                (16 * mm + r16) * 528 + kk * 64 + q * 16);
#pragma unroll
    for (int nn = 0; nn < 4; ++nn) {
      f32x4 acc = {0.f, 0.f, 0.f, 0.f};
#pragma unroll
      for (int kk = 0; kk < 8; ++kk)
        acc = __builtin_amdgcn_mfma_f32_16x16x32_bf16(afr[nn][kk], bfr[kk], acc, 0, 0, 0);
      const int m  = m0 + 16 * mm + r16;
      const int j0 = 64 * wv + 16 * nn + 4 * q;
      f32x4 v = acc + bs[nn];
      *(f32x4*)(out + (size_t)m * HDIM + j0) = v;
    }
  }
}

// ---------------------------------------------------------------------------
// Phase 2: recurrence, in place on out (out holds xw from phase 1).
// 4 WGs x 16 batches (fills MFMA M=16), 4 waves x 4 j-tiles each.
// Batch groups are fully independent -> no cross-WG sync.
// h state: bf16 in LDS, double buffered, one barrier/step.
// W_hh bf16 fragments pinned in registers for all 2048 steps.
// ---------------------------------------------------------------------------
__global__ __launch_bounds__(256, 1) void rnn_recur(
    const float* __restrict__ w_hh, float* out)
{
  __shared__ __align__(16) unsigned short hbuf[2 * 16 * 264];
  const int tid  = threadIdx.x;
  const int wv   = tid >> 6;
  const int lane = tid & 63;
  const int q    = lane >> 4;
  const int r16  = lane & 15;
  const int g    = blockIdx.x;          // batch group: batches [16g, 16g+16)

  s16x8 afr[4][8];
#pragma unroll
  for (int nn = 0; nn < 4; ++nn) {
    const int j = 64 * wv + 16 * nn + r16;
#pragma unroll
    for (int kk = 0; kk < 8; ++kk) {
      const int k0 = kk * 32 + q * 8;
      f32x4 lo = *(const f32x4*)(w_hh + j * HDIM + k0);
      f32x4 hi = *(const f32x4*)(w_hh + j * HDIM + k0 + 4);
      union { s16x8 v; uint32_t u[4]; } fu;
      fu.u[0] = cvt_pk_bf16(lo.x, lo.y);
      fu.u[1] = cvt_pk_bf16(lo.z, lo.w);
      fu.u[2] = cvt_pk_bf16(hi.x, hi.y);
      fu.u[3] = cvt_pk_bf16(hi.z, hi.w);
      afr[nn][kk] = fu.v;
    }
  }

  // h0 = 0 (both buffers)
  for (int i = tid; i < 2 * 16 * 264; i += 256) hbuf[i] = 0;

  const int brow = (16 * g + r16) * HDIM;   // this lane's batch row base
  __syncthreads();

  // preload xw for t=0
  f32x4 xw_cur[4];
#pragma unroll
  for (int nn = 0; nn < 4; ++nn)
    xw_cur[nn] = *(const f32x4*)(out + brow + 64 * wv + 16 * nn + 4 * q);

  int p = 0;
  for (int t = 0; t < T_SEQ; ++t) {
    // prefetch xw for t+1 (t=T-1 loads an already-overwritten t=0 row; unused)
    const size_t tn = (size_t)((t + 1 < T_SEQ) ? (t + 1) : 0) * (BATCH * HDIM);
    f32x4 xw_nxt[4];
#pragma unroll
    for (int nn = 0; nn < 4; ++nn)
      xw_nxt[nn] = *(const f32x4*)(out + tn + brow + 64 * wv + 16 * nn + 4 * q);

    // B-fragments: lane l reads h[b = l&15][k-run], contiguous 16B
    const char* hb = (const char*)hbuf + p * (16 * 264 * 2);
    s16x8 bfr[8];
#pragma unroll
    for (int kk = 0; kk < 8; ++kk)
      bfr[kk] = *(const s16x8*)(hb + r16 * 528 + kk * 64 + q * 16);

    char* hw = (char*)hbuf + (p ^ 1) * (16 * 264 * 2);
    const size_t tc = (size_t)t * (BATCH * HDIM);
#pragma unroll
    for (int nn = 0; nn < 4; ++nn) {
      f32x4 acc = {0.f, 0.f, 0.f, 0.f};
#pragma unroll
      for (int kk = 0; kk < 8; ++kk)
        acc = __builtin_amdgcn_mfma_f32_16x16x32_bf16(afr[nn][kk], bfr[kk], acc, 0, 0, 0);
      const int j0 = 64 * wv + 16 * nn + 4 * q;
      f32x4 v;
      v.x = fast_tanh(acc.x + xw_cur[nn].x);
      v.y = fast_tanh(acc.y + xw_cur[nn].y);
      v.z = fast_tanh(acc.z + xw_cur[nn].z);
      v.w = fast_tanh(acc.w + xw_cur[nn].w);
      *(f32x4*)(out + tc + brow + j0) = v;          // in-place over xw[t]
      u32x2 pk;
      pk.x = cvt_pk_bf16(v.x, v.y);
      pk.y = cvt_pk_bf16(v.z, v.w);
      *(u32x2*)(hw + r16 * 528 + j0 * 2) = pk;      // h state for t+1
    }
    __syncthreads();
#pragma unroll
    for (int nn = 0; nn < 4; ++nn) xw_cur[nn] = xw_nxt[nn];
    p ^= 1;
  }
}

extern "C" void kernel_launch(void* const* d_in, const int* in_sizes, int n_in,
                              void* d_out, int out_size, void* d_ws, size_t ws_size,
                              hipStream_t stream) {
  (void)in_sizes; (void)n_in; (void)d_ws; (void)ws_size; (void)out_size;
  const float* x    = (const float*)d_in[0];
  const float* w_ih = (const float*)d_in[1];
  const float* w_hh = (const float*)d_in[2];
  const float* b_ih = (const float*)d_in[3];
  const float* b_hh = (const float*)d_in[4];
  float* out = (float*)d_out;

  rnn_xproj<<<dim3(131072 / 64), dim3(256), 0, stream>>>(x, w_ih, b_ih, b_hh, out);
  rnn_recur<<<dim3(4), dim3(256), 0, stream>>>(w_hh, out);
}

// Round 7
// 2232.230 us; speedup vs baseline: 1.0986x; 1.0986x over previous
//
#include <hip/hip_runtime.h>
#include <cstdint>
#include <cstddef>

#define T_SEQ 2048
#define BATCH 64
#define DIN   256
#define HDIM  256

typedef float    f32x4 __attribute__((ext_vector_type(4)));
typedef short    s16x8 __attribute__((ext_vector_type(8)));
typedef uint32_t u32x2 __attribute__((ext_vector_type(2)));

// f32 pair -> packed bf16 (RNE); no builtin on gfx950 -> asm
__device__ inline uint32_t cvt_pk_bf16(float lo, float hi) {
  uint32_t r;
  asm("v_cvt_pk_bf16_f32 %0, %1, %2" : "=v"(r) : "v"(lo), "v"(hi));
  return r;
}

// tanh(x) = 1 - 2/(1+e^{2x}); e^{2x} = exp2(2*log2(e)*x). Saturates right.
__device__ inline float fast_tanh(float x) {
  float s = x * 2.885390081777927f;   // 2/ln(2)
  float e2, r;
  asm("v_exp_f32 %0, %1" : "=v"(e2) : "v"(s));
  float d = 1.0f + e2;
  asm("v_rcp_f32 %0, %1" : "=v"(r) : "v"(d));
  return __builtin_fmaf(-2.0f, r, 1.0f);
}

// ---------------------------------------------------------------------------
// Phase 1: out[m][j] = sum_i x[m][i]*w_ih[j][i] + b_ih[j] + b_hh[j]
// ---------------------------------------------------------------------------
__global__ __launch_bounds__(256) void rnn_xproj(
    const float* __restrict__ x, const float* __restrict__ w_ih,
    const float* __restrict__ b_ih, const float* __restrict__ b_hh,
    float* __restrict__ out)
{
  __shared__ __align__(16) unsigned short xtile[64 * 264]; // 528B row stride
  const int tid  = threadIdx.x;
  const int wv   = tid >> 6;
  const int lane = tid & 63;
  const int q    = lane >> 4;
  const int r16  = lane & 15;
  const int m0   = blockIdx.x * 64;

  s16x8 afr[4][8];
#pragma unroll
  for (int nn = 0; nn < 4; ++nn) {
    const int j = 64 * wv + 16 * nn + r16;
#pragma unroll
    for (int kk = 0; kk < 8; ++kk) {
      const int k0 = kk * 32 + q * 8;
      f32x4 lo = *(const f32x4*)(w_ih + j * DIN + k0);
      f32x4 hi = *(const f32x4*)(w_ih + j * DIN + k0 + 4);
      union { s16x8 v; uint32_t u[4]; } fu;
      fu.u[0] = cvt_pk_bf16(lo.x, lo.y);
      fu.u[1] = cvt_pk_bf16(lo.z, lo.w);
      fu.u[2] = cvt_pk_bf16(hi.x, hi.y);
      fu.u[3] = cvt_pk_bf16(hi.z, hi.w);
      afr[nn][kk] = fu.v;
    }
  }

  f32x4 bs[4];
#pragma unroll
  for (int nn = 0; nn < 4; ++nn) {
    const int j0 = 64 * wv + 16 * nn + 4 * q;
    f32x4 a = *(const f32x4*)(b_ih + j0);
    f32x4 b = *(const f32x4*)(b_hh + j0);
    bs[nn] = a + b;
  }

#pragma unroll
  for (int s = 0; s < 16; ++s) {
    const int o   = s * 1024 + tid * 4;
    const int row = o >> 8;
    const int col = o & 255;
    f32x4 v = *(const f32x4*)(x + (size_t)m0 * DIN + o);
    u32x2 pk;
    pk.x = cvt_pk_bf16(v.x, v.y);
    pk.y = cvt_pk_bf16(v.z, v.w);
    *(u32x2*)((char*)xtile + row * 528 + col * 2) = pk;
  }
  __syncthreads();

#pragma unroll
  for (int mm = 0; mm < 4; ++mm) {
    s16x8 bfr[8];
#pragma unroll
    for (int kk = 0; kk < 8; ++kk)
      bfr[kk] = *(const s16x8*)((const char*)xtile +
                                (16 * mm + r16) * 528 + kk * 64 + q * 16);
#pragma unroll
    for (int nn = 0; nn < 4; ++nn) {
      f32x4 acc = {0.f, 0.f, 0.f, 0.f};
#pragma unroll
      for (int kk = 0; kk < 8; ++kk)
        acc = __builtin_amdgcn_mfma_f32_16x16x32_bf16(afr[nn][kk], bfr[kk], acc, 0, 0, 0);
      const int m  = m0 + 16 * mm + r16;
      const int j0 = 64 * wv + 16 * nn + 4 * q;
      f32x4 v = acc + bs[nn];
      *(f32x4*)(out + (size_t)m * HDIM + j0) = v;
    }
  }
}

// ---------------------------------------------------------------------------
// Phase 2: recurrence, in place on out (out holds xw from phase 1).
// 8 WGs x 8 batches. 8 waves x 2 j-tiles (j = 32*wv .. +32).
// MFMA M=16 runs with rows 8..15 as broadcast duplicates of rows 0..7
// (same-address LDS reads broadcast; their outputs are never stored).
// Per step: ds_read h -> 16 MFMA/wave -> tanh -> store + bf16 h ds_write ->
// lgkmcnt(0) + raw s_barrier (NO vmcnt drain: xw prefetch stays in flight).
// xw prefetched 2 steps ahead to cover HBM latency.
// ---------------------------------------------------------------------------
__global__ __launch_bounds__(512, 2) void rnn_recur(
    const float* __restrict__ w_hh, float* out)
{
  __shared__ __align__(16) unsigned short hbuf[2 * 16 * 264]; // 528B row stride
  const int tid  = threadIdx.x;
  const int wv   = tid >> 6;       // 0..7
  const int lane = tid & 63;
  const int q    = lane >> 4;
  const int r16  = lane & 15;
  const int r8   = r16 & 7;
  const int g    = blockIdx.x;     // batch group: batches [8g, 8g+8)

  // A-fragments: lane holds W_hh[j = 32wv+16nn+r16][k-chunk], bf16, pinned.
  s16x8 afr[2][8];
#pragma unroll
  for (int nn = 0; nn < 2; ++nn) {
    const int j = 32 * wv + 16 * nn + r16;
#pragma unroll
    for (int kk = 0; kk < 8; ++kk) {
      const int k0 = kk * 32 + q * 8;
      f32x4 lo = *(const f32x4*)(w_hh + j * HDIM + k0);
      f32x4 hi = *(const f32x4*)(w_hh + j * HDIM + k0 + 4);
      union { s16x8 v; uint32_t u[4]; } fu;
      fu.u[0] = cvt_pk_bf16(lo.x, lo.y);
      fu.u[1] = cvt_pk_bf16(lo.z, lo.w);
      fu.u[2] = cvt_pk_bf16(hi.x, hi.y);
      fu.u[3] = cvt_pk_bf16(hi.z, hi.w);
      afr[nn][kk] = fu.v;
    }
  }

  // h0 = 0 (both buffers; rows 8..15 stay 0 forever but are never read)
  for (int i = tid; i < 2 * 16 * 264; i += 512) hbuf[i] = 0;
  __syncthreads();

  const int browL = (8 * g + r8)  * HDIM;  // xw load row (dup for r16>=8)
  const int browS = (8 * g + r16) * HDIM;  // store row (valid iff r16<8)
  const int jA = 32 * wv + 4 * q;          // nn=0 column base
  const int jB = jA + 16;                  // nn=1 column base
  const size_t STEP = (size_t)BATCH * HDIM;

  f32x4 xwA_c = *(const f32x4*)(out + browL + jA);
  f32x4 xwB_c = *(const f32x4*)(out + browL + jB);
  f32x4 xwA_n = *(const f32x4*)(out + STEP + browL + jA);
  f32x4 xwB_n = *(const f32x4*)(out + STEP + browL + jB);

  int p = 0;
  for (int t = 0; t < T_SEQ; ++t) {
    // prefetch xw[t+2] (tail iterations read overwritten rows; unused, finite)
    const int tf = (t + 2 < T_SEQ) ? (t + 2) : (t + 2 - T_SEQ);
    const size_t fo = (size_t)tf * STEP + browL;
    f32x4 xwA_f = *(const f32x4*)(out + fo + jA);
    f32x4 xwB_f = *(const f32x4*)(out + fo + jB);

    // B-fragments: rows 0..7, lanes r16>=8 broadcast-read row r8
    const char* hb = (const char*)hbuf + p * (16 * 264 * 2);
    s16x8 bfr[8];
#pragma unroll
    for (int kk = 0; kk < 8; ++kk)
      bfr[kk] = *(const s16x8*)(hb + r8 * 528 + kk * 64 + q * 16);

    char* hw = (char*)hbuf + (p ^ 1) * (16 * 264 * 2);
    const size_t tc = (size_t)t * STEP;

    f32x4 accA = {0.f, 0.f, 0.f, 0.f};
    f32x4 accB = {0.f, 0.f, 0.f, 0.f};
#pragma unroll
    for (int kk = 0; kk < 8; ++kk) {
      accA = __builtin_amdgcn_mfma_f32_16x16x32_bf16(afr[0][kk], bfr[kk], accA, 0, 0, 0);
      accB = __builtin_amdgcn_mfma_f32_16x16x32_bf16(afr[1][kk], bfr[kk], accB, 0, 0, 0);
    }

    f32x4 vA, vB;
    vA.x = fast_tanh(accA.x + xwA_c.x);
    vA.y = fast_tanh(accA.y + xwA_c.y);
    vA.z = fast_tanh(accA.z + xwA_c.z);
    vA.w = fast_tanh(accA.w + xwA_c.w);
    vB.x = fast_tanh(accB.x + xwB_c.x);
    vB.y = fast_tanh(accB.y + xwB_c.y);
    vB.z = fast_tanh(accB.z + xwB_c.z);
    vB.w = fast_tanh(accB.w + xwB_c.w);

    if (r16 < 8) {
      *(f32x4*)(out + tc + browS + jA) = vA;       // in-place over xw[t]
      *(f32x4*)(out + tc + browS + jB) = vB;
      u32x2 pkA, pkB;
      pkA.x = cvt_pk_bf16(vA.x, vA.y);
      pkA.y = cvt_pk_bf16(vA.z, vA.w);
      pkB.x = cvt_pk_bf16(vB.x, vB.y);
      pkB.y = cvt_pk_bf16(vB.z, vB.w);
      *(u32x2*)(hw + r16 * 528 + jA * 2) = pkA;    // h for t+1
      *(u32x2*)(hw + r16 * 528 + jB * 2) = pkB;
    }

    // order LDS h-exchange only; do NOT drain vmcnt (prefetch stays in flight)
    asm volatile("s_waitcnt lgkmcnt(0)" ::: "memory");
    __builtin_amdgcn_s_barrier();
    __builtin_amdgcn_sched_barrier(0);

    xwA_c = xwA_n; xwB_c = xwB_n;
    xwA_n = xwA_f; xwB_n = xwB_f;
    p ^= 1;
  }
}

extern "C" void kernel_launch(void* const* d_in, const int* in_sizes, int n_in,
                              void* d_out, int out_size, void* d_ws, size_t ws_size,
                              hipStream_t stream) {
  (void)in_sizes; (void)n_in; (void)d_ws; (void)ws_size; (void)out_size;
  const float* x    = (const float*)d_in[0];
  const float* w_ih = (const float*)d_in[1];
  const float* w_hh = (const float*)d_in[2];
  const float* b_ih = (const float*)d_in[3];
  const float* b_hh = (const float*)d_in[4];
  float* out = (float*)d_out;

  rnn_xproj<<<dim3(131072 / 64), dim3(256), 0, stream>>>(x, w_ih, b_ih, b_hh, out);
  rnn_recur<<<dim3(8), dim3(512), 0, stream>>>(w_hh, out);
}